// Round 15
// baseline (228.975 us; speedup 1.0000x reference)
//
#include <hip/hip_runtime.h>

// GCN forward: fixed-capacity bucket-sort CSR + MFMA GEMMs (bf16, fp32 accum)
// + gather aggregation (readlane walk). Layer-1 messages stored CHANNEL-SPLIT
// (two n x 64 half-arrays) and aggregated with an XCD-aware block swizzle so
// each XCD streams only one half-array (halves compulsory cross-XCD traffic).
// x1 == x2 (dropout identity) => single branch; output projection folded into
// layer-2 weights:
//   W2' = W2 @ (linW_top + linW_bot),  b' = b2 @ (linW_top+linW_bot) + linb
//   h1s[i]  = inv[i] * (x @ W1)[i]                       (bf16, split layout)
//   agg1[i] = relu( inv[i]*(sum_{N+(i)} h1s[s]) + b1 )   (bf16 row-major)
//   h2p[i]  = inv[i] * (agg1 @ W2')[i]                   (bf16, MFMA)
//   out     = log_softmax( inv[i]*(sum_{N+(i)} h2p[s]) + b' )
// Buckets: 256 dst nodes, FIXED capacity 8192. Assumes n <= 65536.

#define CIN  128
#define CHID 128
#define COUT 64
#define BCAP_SH 13           // bucket capacity 8192 entries
#define BCAP    (1 << BCAP_SH)
#define BINCHUNK 2048        // small chunks -> 391 blocks -> latency hiding

typedef short v8s __attribute__((ext_vector_type(8)));
typedef float v4f __attribute__((ext_vector_type(4)));

static __device__ __forceinline__ unsigned short f2bf(float f) {
    unsigned int u = __float_as_uint(f);
    unsigned int r = (u + 0x7fffu + ((u >> 16) & 1u)) >> 16;  // RNE
    return (unsigned short)r;
}
static __device__ __forceinline__ float bf2f(unsigned short v) {
    return __uint_as_float(((unsigned int)v) << 16);
}

// ---------------- bin edges into fixed-cap bucket regions ----------------
__global__ __launch_bounds__(256) void bin_kernel(const int* __restrict__ src,
                                                  const int* __restrict__ dst,
                                                  int* __restrict__ bcursor,
                                                  unsigned int* __restrict__ binned, int E) {
    __shared__ int h[256];
    __shared__ int base[256];
    int t = threadIdx.x;
    h[t] = 0;
    __syncthreads();
    int e0 = blockIdx.x * BINCHUNK;
    int e1 = e0 + BINCHUNK; if (e1 > E) e1 = E;
    for (int e = e0 + t; e < e1; e += 256)
        atomicAdd(&h[dst[e] >> 8], 1);
    __syncthreads();
    int c = h[t];
    base[t] = (t << BCAP_SH) + (c ? atomicAdd(&bcursor[t], c) : 0);
    __syncthreads();
    h[t] = 0;
    __syncthreads();
    for (int e = e0 + t; e < e1; e += 256) {
        int d = dst[e];
        int b = d >> 8;
        int pos = base[b] + atomicAdd(&h[b], 1);
        binned[pos] = (unsigned int)src[e] | (((unsigned int)d & 255u) << 16);
    }
}

// ---------------- per-bucket CSR build (deg->inv, rowpair, ebuf), 512 thr ------
__global__ __launch_bounds__(512) void csr_kernel(const unsigned int* __restrict__ binned,
                                                  const int* __restrict__ bcursor,
                                                  int2* __restrict__ rowpair,
                                                  float* __restrict__ inv,
                                                  int* __restrict__ ebuf, int n) {
    __shared__ int h[256];
    __shared__ int s[256];
    int b = blockIdx.x;
    int t = threadIdx.x;
    int base = b << BCAP_SH;
    int cnt  = bcursor[b];
    if (t < 256) h[t] = 0;
    __syncthreads();
    for (int i = t; i < cnt; i += 512)
        atomicAdd(&h[binned[base + i] >> 16], 1);
    __syncthreads();
    int myc = (t < 256) ? h[t] : 0;
    if (t < 256) s[t] = myc;
    __syncthreads();
    for (int off = 1; off < 256; off <<= 1) {
        int u = (t >= off && t < 256) ? s[t - off] : 0;
        __syncthreads();
        if (t < 256) s[t] += u;
        __syncthreads();
    }
    if (t < 256) {
        int excl = s[t] - myc;
        int node = (b << 8) + t;
        if (node < n) {
            rowpair[node] = make_int2(base + excl, base + excl + myc);
            inv[node] = rsqrtf((float)(myc + 1));  // +1: self-loop
        }
        h[t] = base + excl;  // cursor
    }
    __syncthreads();
    for (int i = t; i < cnt; i += 512) {
        unsigned int v = binned[base + i];
        int pos = atomicAdd(&h[v >> 16], 1);
        ebuf[pos] = (int)(v & 0xffffu);
    }
}

// ---------------- fused weight prep + bcursor zeroing ----------------
__global__ __launch_bounds__(128) void wprep_kernel(const float* __restrict__ W1,
                                                    const float* __restrict__ W2,
                                                    const float* __restrict__ b2,
                                                    const float* __restrict__ linW,
                                                    const float* __restrict__ linb,
                                                    unsigned short* __restrict__ Wt1,
                                                    unsigned short* __restrict__ Wt2,
                                                    float* __restrict__ bp,
                                                    int* __restrict__ bcursor) {
    int b = blockIdx.x;   // 0..128
    int t = threadIdx.x;  // 0..127
    if (b < CHID) {
        Wt1[b * CIN + t] = f2bf(W1[t * CHID + b]);
        if (t < COUT) {
            float acc = 0.f;
#pragma unroll 8
            for (int k = 0; k < COUT; ++k) {
                float wsv = linW[k * COUT + t] + linW[(k + COUT) * COUT + t];
                acc = fmaf(W2[b * COUT + k], wsv, acc);
            }
            Wt2[t * CHID + b] = f2bf(acc);
        }
    } else {
        bcursor[t] = 0;
        bcursor[128 + t] = 0;
        if (t < COUT) {
            float acc = 0.f;
#pragma unroll 8
            for (int k = 0; k < COUT; ++k) {
                float wsv = linW[k * COUT + t] + linW[(k + COUT) * COUT + t];
                acc = fmaf(b2[k], wsv, acc);
            }
            bp[t] = acc + linb[t];
        }
    }
}

// ---------------- MFMA GEMM: H[i] = inv[i] * (A @ Wt^T)[i], bf16 out ----------
// SPLIT (layer 1): output channel c of row r goes to H[(c>>6)*n*64 + r*64 + (c&63)]
// (two half-channel arrays). Otherwise row-major n x NOUT.
template <int NOUT, bool A_BF16, bool SPLIT>
__global__ __launch_bounds__(256) void gemm_mfma(const void* __restrict__ Aptr,
                                                 const unsigned short* __restrict__ Wt,
                                                 const float* __restrict__ inv,
                                                 unsigned short* __restrict__ H, int n) {
    constexpr int NCT = NOUT / 16;
    int lane = threadIdx.x & 63;
    int wave = threadIdx.x >> 6;
    int quad = lane >> 4, r16 = lane & 15;
    int row0 = (blockIdx.x * 4 + wave) * 16;
    if (row0 >= n) return;
    int arow = row0 + r16;
    if (arow >= n) arow = n - 1;  // clamp (safe: result masked by orow<n)

    v4f acc[NCT];
#pragma unroll
    for (int c = 0; c < NCT; ++c) acc[c] = (v4f){0.f, 0.f, 0.f, 0.f};

#pragma unroll
    for (int kc = 0; kc < 4; ++kc) {
        v8s af;
        if (A_BF16) {
            const unsigned short* A = (const unsigned short*)Aptr;
            af = *(const v8s*)(A + (size_t)arow * 128 + kc * 32 + quad * 8);
        } else {
            const float* A = (const float*)Aptr;
            const float4* ap = (const float4*)(A + (size_t)arow * 128 + kc * 32 + quad * 8);
            float4 a0 = ap[0], a1 = ap[1];
            af[0] = (short)f2bf(a0.x); af[1] = (short)f2bf(a0.y);
            af[2] = (short)f2bf(a0.z); af[3] = (short)f2bf(a0.w);
            af[4] = (short)f2bf(a1.x); af[5] = (short)f2bf(a1.y);
            af[6] = (short)f2bf(a1.z); af[7] = (short)f2bf(a1.w);
        }
#pragma unroll
        for (int ct = 0; ct < NCT; ++ct) {
            v8s bf = *(const v8s*)(Wt + (size_t)(ct * 16 + r16) * 128 + kc * 32 + quad * 8);
            acc[ct] = __builtin_amdgcn_mfma_f32_16x16x32_bf16(af, bf, acc[ct], 0, 0, 0);
        }
    }

    // epilogue: row = quad*4 + i (C/D layout), col = ct*16 + r16
    float4 iv = ((const float4*)(inv + row0))[quad];
#pragma unroll
    for (int ct = 0; ct < NCT; ++ct) {
#pragma unroll
        for (int i = 0; i < 4; ++i) {
            int orow = row0 + quad * 4 + i;
            if (orow < n) {
                float sc = (i == 0) ? iv.x : (i == 1) ? iv.y : (i == 2) ? iv.z : iv.w;
                int col = ct * 16 + r16;
                size_t idx = SPLIT
                    ? ((size_t)(col >> 6) * n * 64 + (size_t)orow * 64 + (col & 63))
                    : ((size_t)orow * NOUT + col);
                H[idx] = f2bf(acc[ct][i] * sc);
            }
        }
    }
}

// ---------------- layer-1 aggregate: wave/(node,half), XCD-aware swizzle --------
// Hs: split layout [2][n][64] bf16. Block g: oct=g>>3, pos=g&7, half=pos>>2,
// nodeblk=oct*4+(pos&3). With round-robin block->XCD, XCDs 0-3 touch only
// half 0's array, XCDs 4-7 only half 1's -> per-XCD compulsory stream halves.
__global__ void agg1_kernel(const unsigned short* __restrict__ Hs, const int* __restrict__ ebuf,
                            const int2* __restrict__ rowpair, const float* __restrict__ inv,
                            const float* __restrict__ bias, unsigned short* __restrict__ outp,
                            int n) {
    int g = blockIdx.x;
    int oct = g >> 3, pos = g & 7;
    int half = pos >> 2;
    int node = __builtin_amdgcn_readfirstlane((oct * 4 + (pos & 3)) * 4 + (threadIdx.x >> 6));
    int lane = threadIdx.x & 63;
    if (node >= n) return;
    const unsigned short* H = Hs + (size_t)half * n * 64;
    int2 rp = rowpair[node];                         // uniform -> s_load_dwordx2
    int beg = rp.x, len = rp.y - rp.x;
    int eid = ebuf[beg + lane];                      // coalesced preload
    int m = len < 64 ? len : 64;
    float acc = 0.f;
    int k = 0;
    for (; k + 8 <= m; k += 8) {
        int s0 = __builtin_amdgcn_readlane(eid, k);
        int s1 = __builtin_amdgcn_readlane(eid, k + 1);
        int s2 = __builtin_amdgcn_readlane(eid, k + 2);
        int s3 = __builtin_amdgcn_readlane(eid, k + 3);
        int s4 = __builtin_amdgcn_readlane(eid, k + 4);
        int s5 = __builtin_amdgcn_readlane(eid, k + 5);
        int s6 = __builtin_amdgcn_readlane(eid, k + 6);
        int s7 = __builtin_amdgcn_readlane(eid, k + 7);
        float v0 = bf2f(H[(size_t)s0 * 64 + lane]);
        float v1 = bf2f(H[(size_t)s1 * 64 + lane]);
        float v2 = bf2f(H[(size_t)s2 * 64 + lane]);
        float v3 = bf2f(H[(size_t)s3 * 64 + lane]);
        float v4 = bf2f(H[(size_t)s4 * 64 + lane]);
        float v5 = bf2f(H[(size_t)s5 * 64 + lane]);
        float v6 = bf2f(H[(size_t)s6 * 64 + lane]);
        float v7 = bf2f(H[(size_t)s7 * 64 + lane]);
        acc += ((v0 + v1) + (v2 + v3)) + ((v4 + v5) + (v6 + v7));
    }
    for (; k < m; ++k) {
        int s = __builtin_amdgcn_readlane(eid, k);
        acc += bf2f(H[(size_t)s * 64 + lane]);
    }
    for (; k < len; ++k)                             // deg > 64 fallback (rare)
        acc += bf2f(H[(size_t)ebuf[beg + k] * 64 + lane]);
    acc += bf2f(H[(size_t)node * 64 + lane]);        // self-loop
    float wd = inv[node];
    float o = fmaxf(fmaf(wd, acc, bias[half * 64 + lane]), 0.f);
    outp[(size_t)node * 128 + half * 64 + lane] = f2bf(o);  // row-major for gemm2
}

// ---------------- layer-2 aggregate + bias + log_softmax (readlane walk) ------
__global__ void agg2_final_kernel(const unsigned short* __restrict__ Hs,
                                  const int* __restrict__ ebuf, const int2* __restrict__ rowpair,
                                  const float* __restrict__ inv, const float* __restrict__ bp,
                                  float* __restrict__ outp, int n) {
    int node = __builtin_amdgcn_readfirstlane(blockIdx.x * 4 + (threadIdx.x >> 6));
    int lane = threadIdx.x & 63;
    if (node >= n) return;
    int2 rp = rowpair[node];
    int beg = rp.x, len = rp.y - rp.x;
    int eid = ebuf[beg + lane];
    int m = len < 64 ? len : 64;
    float acc = 0.f;
    int k = 0;
    for (; k + 4 <= m; k += 4) {
        int s0 = __builtin_amdgcn_readlane(eid, k);
        int s1 = __builtin_amdgcn_readlane(eid, k + 1);
        int s2 = __builtin_amdgcn_readlane(eid, k + 2);
        int s3 = __builtin_amdgcn_readlane(eid, k + 3);
        float v0 = bf2f(Hs[(size_t)s0 * 64 + lane]);
        float v1 = bf2f(Hs[(size_t)s1 * 64 + lane]);
        float v2 = bf2f(Hs[(size_t)s2 * 64 + lane]);
        float v3 = bf2f(Hs[(size_t)s3 * 64 + lane]);
        acc += (v0 + v1) + (v2 + v3);
    }
    for (; k < m; ++k) {
        int s = __builtin_amdgcn_readlane(eid, k);
        acc += bf2f(Hs[(size_t)s * 64 + lane]);
    }
    for (; k < len; ++k)                             // deg > 64 fallback
        acc += bf2f(Hs[(size_t)ebuf[beg + k] * 64 + lane]);
    acc += bf2f(Hs[(size_t)node * 64 + lane]);       // self-loop
    float fo = fmaf(inv[node], acc, bp[lane]);
    float mx = fo;
#pragma unroll
    for (int off = 32; off >= 1; off >>= 1) mx = fmaxf(mx, __shfl_xor(mx, off, 64));
    float ex = expf(fo - mx);
    float s = ex;
#pragma unroll
    for (int off = 32; off >= 1; off >>= 1) s += __shfl_xor(s, off, 64);
    outp[(size_t)node * COUT + lane] = fo - mx - logf(s);
}

static inline size_t align16(size_t x) { return (x + 15) & ~(size_t)15; }

extern "C" void kernel_launch(void* const* d_in, const int* in_sizes, int n_in,
                              void* d_out, int out_size, void* d_ws, size_t ws_size,
                              hipStream_t stream) {
    const float* x    = (const float*)d_in[0];
    const int*   eidx = (const int*)d_in[1];
    const float* W1   = (const float*)d_in[2];
    const float* b1   = (const float*)d_in[3];
    const float* W2   = (const float*)d_in[4];
    const float* b2   = (const float*)d_in[5];
    const float* linW = (const float*)d_in[6];
    const float* linb = (const float*)d_in[7];
    float* out = (float*)d_out;

    const int n = in_sizes[0] / CIN;   // 50000
    const int E = in_sizes[1] / 2;     // 800000
    const int* src = eidx;
    const int* dst = eidx + E;
    const int NBKT = (n + 255) >> 8;   // 196

    // ---- workspace carve-up
    char* ws = (char*)d_ws;
    size_t off = 0;
    int2*  rowpair = (int2*)(ws + off);  off = align16(off + (size_t)n * 8);
    float* inv     = (float*)(ws + off); off = align16(off + (size_t)n * 4);
    int*   bcursor = (int*)(ws + off);   off = align16(off + 256 * 4);
    unsigned short* Wt1 = (unsigned short*)(ws + off); off = align16(off + (size_t)CHID * CIN * 2);
    unsigned short* Wt2 = (unsigned short*)(ws + off); off = align16(off + (size_t)COUT * CHID * 2);
    float* bp      = (float*)(ws + off); off = align16(off + (size_t)COUT * 4);
    unsigned int* binned = (unsigned int*)(ws + off); off = align16(off + (size_t)256 * BCAP * 4);
    int*   ebuf    = (int*)(ws + off);   off = align16(off + (size_t)256 * BCAP * 4);
    unsigned short* h1s   = (unsigned short*)(ws + off); off = align16(off + (size_t)n * CHID * 2);
    unsigned short* agg1b = (unsigned short*)(ws + off); off = align16(off + (size_t)n * CHID * 2);
    unsigned short* h2p   = (unsigned short*)(ws + off); off = align16(off + (size_t)n * COUT * 2);

    // ---- weight prep + bcursor zeroing (single launch, replaces memset)
    wprep_kernel<<<CHID + 1, 128, 0, stream>>>(W1, W2, b2, linW, linb, Wt1, Wt2, bp, bcursor);

    // ---- CSR build: bin (fixed-cap regions) -> per-bucket CSR
    bin_kernel<<<(E + BINCHUNK - 1) / BINCHUNK, 256, 0, stream>>>(src, dst, bcursor, binned, E);
    csr_kernel<<<NBKT, 512, 0, stream>>>(binned, bcursor, rowpair, inv, ebuf, n);

    // ---- layer 1: MFMA GEMM (split out) + channel-split aggregate (XCD swizzle)
    gemm_mfma<CHID, false, true><<<(n + 63) / 64, 256, 0, stream>>>(x, Wt1, inv, h1s, n);
    {
        int octs = (n + 15) / 16;   // each oct = 8 blocks = 4 nodeblocks x 2 halves
        agg1_kernel<<<octs * 8, 256, 0, stream>>>(h1s, ebuf, rowpair, inv, b1, agg1b, n);
    }

    // ---- layer 2: MFMA GEMM (bf16 A, row-major out) + final
    gemm_mfma<COUT, true, false><<<(n + 63) / 64, 256, 0, stream>>>(agg1b, Wt2, inv, h2p, n);
    agg2_final_kernel<<<(n + 3) / 4, 256, 0, stream>>>(h2p, ebuf, rowpair, inv, bp, out, n);
}

// Round 16
// 215.601 us; speedup vs baseline: 1.0620x; 1.0620x over previous
//
#include <hip/hip_runtime.h>

// GCN forward: fixed-capacity bucket-sort CSR + MFMA GEMMs (bf16, fp32 accum)
// + gather aggregation with vector-preloaded edge ids (readlane walk).
// x1 == x2 (dropout identity) => single branch; output projection folded into
// layer-2 weights:
//   W2' = W2 @ (linW_top + linW_bot),  b' = b2 @ (linW_top+linW_bot) + linb
//   h1s[i]  = inv[i] * (x @ W1)[i]                       (bf16, MFMA)
//   agg1[i] = relu( inv[i]*(sum_{N+(i)} h1s[s]) + b1 )   (bf16 out)
//   h2p[i]  = inv[i] * (agg1 @ W2')[i]                   (bf16, MFMA)
//   out     = log_softmax( inv[i]*(sum_{N+(i)} h2p[s]) + b' )
// Buckets: 256 dst nodes each, FIXED capacity 8192 (mean 4096, Poisson sigma
// 64 -> overflow prob ~0). Assumes n <= 65536 (src ids pack in 16 bits).

#define CIN  128
#define CHID 128
#define COUT 64
#define BCAP_SH 13           // bucket capacity 8192 entries
#define BCAP    (1 << BCAP_SH)
#define BINCHUNK 2048        // small chunks -> 391 blocks -> latency hiding

typedef short v8s __attribute__((ext_vector_type(8)));
typedef float v4f __attribute__((ext_vector_type(4)));

static __device__ __forceinline__ unsigned short f2bf(float f) {
    unsigned int u = __float_as_uint(f);
    unsigned int r = (u + 0x7fffu + ((u >> 16) & 1u)) >> 16;  // RNE
    return (unsigned short)r;
}
static __device__ __forceinline__ float bf2f(unsigned short v) {
    return __uint_as_float(((unsigned int)v) << 16);
}

// ---------------- bin edges into fixed-cap bucket regions ----------------
// Bucket b's region is [b*BCAP, (b+1)*BCAP): bases are compile-time.
__global__ __launch_bounds__(256) void bin_kernel(const int* __restrict__ src,
                                                  const int* __restrict__ dst,
                                                  int* __restrict__ bcursor,
                                                  unsigned int* __restrict__ binned, int E) {
    __shared__ int h[256];
    __shared__ int base[256];
    int t = threadIdx.x;
    h[t] = 0;
    __syncthreads();
    int e0 = blockIdx.x * BINCHUNK;
    int e1 = e0 + BINCHUNK; if (e1 > E) e1 = E;
    for (int e = e0 + t; e < e1; e += 256)
        atomicAdd(&h[dst[e] >> 8], 1);
    __syncthreads();
    int c = h[t];
    base[t] = (t << BCAP_SH) + (c ? atomicAdd(&bcursor[t], c) : 0);
    __syncthreads();
    h[t] = 0;
    __syncthreads();
    for (int e = e0 + t; e < e1; e += 256) {
        int d = dst[e];
        int b = d >> 8;
        int pos = base[b] + atomicAdd(&h[b], 1);
        binned[pos] = (unsigned int)src[e] | (((unsigned int)d & 255u) << 16);
    }
}

// ---------------- per-bucket CSR build (deg->inv, rowpair, ebuf), 512 thr ------
__global__ __launch_bounds__(512) void csr_kernel(const unsigned int* __restrict__ binned,
                                                  const int* __restrict__ bcursor,
                                                  int2* __restrict__ rowpair,
                                                  float* __restrict__ inv,
                                                  int* __restrict__ ebuf, int n) {
    __shared__ int h[256];
    __shared__ int s[256];
    int b = blockIdx.x;
    int t = threadIdx.x;
    int base = b << BCAP_SH;
    int cnt  = bcursor[b];
    if (t < 256) h[t] = 0;
    __syncthreads();
    // phase 1: per-dst hist (512-wide)
    for (int i = t; i < cnt; i += 512)
        atomicAdd(&h[binned[base + i] >> 16], 1);
    __syncthreads();
    int myc = (t < 256) ? h[t] : 0;
    if (t < 256) s[t] = myc;
    __syncthreads();
    // phase 2: scan (first 256 threads; all threads hit barriers)
    for (int off = 1; off < 256; off <<= 1) {
        int u = (t >= off && t < 256) ? s[t - off] : 0;
        __syncthreads();
        if (t < 256) s[t] += u;
        __syncthreads();
    }
    if (t < 256) {
        int excl = s[t] - myc;
        int node = (b << 8) + t;
        if (node < n) {
            rowpair[node] = make_int2(base + excl, base + excl + myc);
            inv[node] = rsqrtf((float)(myc + 1));  // +1: self-loop
        }
        h[t] = base + excl;  // cursor
    }
    __syncthreads();
    // phase 3: scatter src ids (512-wide)
    for (int i = t; i < cnt; i += 512) {
        unsigned int v = binned[base + i];
        int pos = atomicAdd(&h[v >> 16], 1);
        ebuf[pos] = (int)(v & 0xffffu);
    }
}

// ---------------- fused weight prep + bcursor zeroing ----------------
// Blocks 0..127: Wt1 row j=b, plus (t<64) Wt2 row r=b of W2' = W2@Wsum (bf16^T).
// Block 128: (t<64) bp = b2 @ Wsum + linb; all 128 threads zero bcursor.
__global__ __launch_bounds__(128) void wprep_kernel(const float* __restrict__ W1,
                                                    const float* __restrict__ W2,
                                                    const float* __restrict__ b2,
                                                    const float* __restrict__ linW,
                                                    const float* __restrict__ linb,
                                                    unsigned short* __restrict__ Wt1,
                                                    unsigned short* __restrict__ Wt2,
                                                    float* __restrict__ bp,
                                                    int* __restrict__ bcursor) {
    int b = blockIdx.x;   // 0..128
    int t = threadIdx.x;  // 0..127
    if (b < CHID) {
        Wt1[b * CIN + t] = f2bf(W1[t * CHID + b]);
        if (t < COUT) {
            float acc = 0.f;
#pragma unroll 8
            for (int k = 0; k < COUT; ++k) {
                float wsv = linW[k * COUT + t] + linW[(k + COUT) * COUT + t];
                acc = fmaf(W2[b * COUT + k], wsv, acc);
            }
            Wt2[t * CHID + b] = f2bf(acc);
        }
    } else {
        bcursor[t] = 0;
        bcursor[128 + t] = 0;
        if (t < COUT) {
            float acc = 0.f;
#pragma unroll 8
            for (int k = 0; k < COUT; ++k) {
                float wsv = linW[k * COUT + t] + linW[(k + COUT) * COUT + t];
                acc = fmaf(b2[k], wsv, acc);
            }
            bp[t] = acc + linb[t];
        }
    }
}

// ---------------- MFMA GEMM: H[i] = inv[i] * (A @ Wt^T)[i], bf16 out ----------
template <int NOUT, bool A_BF16>
__global__ __launch_bounds__(256) void gemm_mfma(const void* __restrict__ Aptr,
                                                 const unsigned short* __restrict__ Wt,
                                                 const float* __restrict__ inv,
                                                 unsigned short* __restrict__ H, int n) {
    constexpr int NCT = NOUT / 16;
    int lane = threadIdx.x & 63;
    int wave = threadIdx.x >> 6;
    int quad = lane >> 4, r16 = lane & 15;
    int row0 = (blockIdx.x * 4 + wave) * 16;
    if (row0 >= n) return;
    int arow = row0 + r16;
    if (arow >= n) arow = n - 1;  // clamp (safe: result masked by orow<n)

    v4f acc[NCT];
#pragma unroll
    for (int c = 0; c < NCT; ++c) acc[c] = (v4f){0.f, 0.f, 0.f, 0.f};

#pragma unroll
    for (int kc = 0; kc < 4; ++kc) {
        v8s af;
        if (A_BF16) {
            const unsigned short* A = (const unsigned short*)Aptr;
            af = *(const v8s*)(A + (size_t)arow * 128 + kc * 32 + quad * 8);
        } else {
            const float* A = (const float*)Aptr;
            const float4* ap = (const float4*)(A + (size_t)arow * 128 + kc * 32 + quad * 8);
            float4 a0 = ap[0], a1 = ap[1];
            af[0] = (short)f2bf(a0.x); af[1] = (short)f2bf(a0.y);
            af[2] = (short)f2bf(a0.z); af[3] = (short)f2bf(a0.w);
            af[4] = (short)f2bf(a1.x); af[5] = (short)f2bf(a1.y);
            af[6] = (short)f2bf(a1.z); af[7] = (short)f2bf(a1.w);
        }
#pragma unroll
        for (int ct = 0; ct < NCT; ++ct) {
            v8s bf = *(const v8s*)(Wt + (size_t)(ct * 16 + r16) * 128 + kc * 32 + quad * 8);
            acc[ct] = __builtin_amdgcn_mfma_f32_16x16x32_bf16(af, bf, acc[ct], 0, 0, 0);
        }
    }

    // epilogue: row = quad*4 + i (C/D layout), col = ct*16 + r16
    float4 iv = ((const float4*)(inv + row0))[quad];
#pragma unroll
    for (int ct = 0; ct < NCT; ++ct) {
#pragma unroll
        for (int i = 0; i < 4; ++i) {
            int orow = row0 + quad * 4 + i;
            if (orow < n) {
                float sc = (i == 0) ? iv.x : (i == 1) ? iv.y : (i == 2) ? iv.z : iv.w;
                H[(size_t)orow * NOUT + ct * 16 + r16] = f2bf(acc[ct][i] * sc);
            }
        }
    }
}

// ---------------- layer-1 aggregate: wave/node, readlane edge walk ----------
__global__ void agg1_kernel(const unsigned int* __restrict__ Hs, const int* __restrict__ ebuf,
                            const int2* __restrict__ rowpair, const float* __restrict__ inv,
                            const float* __restrict__ bias, unsigned int* __restrict__ outp,
                            int n) {
    int node = __builtin_amdgcn_readfirstlane(blockIdx.x * 4 + (threadIdx.x >> 6));
    int lane = threadIdx.x & 63;
    if (node >= n) return;
    int2 rp = rowpair[node];                         // uniform -> s_load_dwordx2
    int beg = rp.x, len = rp.y - rp.x;
    int eid = ebuf[beg + lane];                      // coalesced preload
    int m = len < 64 ? len : 64;
    float ax = 0.f, ay = 0.f;
    int k = 0;
    for (; k + 4 <= m; k += 4) {
        int s0 = __builtin_amdgcn_readlane(eid, k);
        int s1 = __builtin_amdgcn_readlane(eid, k + 1);
        int s2 = __builtin_amdgcn_readlane(eid, k + 2);
        int s3 = __builtin_amdgcn_readlane(eid, k + 3);
        unsigned int u0 = Hs[(size_t)s0 * 64 + lane];
        unsigned int u1 = Hs[(size_t)s1 * 64 + lane];
        unsigned int u2 = Hs[(size_t)s2 * 64 + lane];
        unsigned int u3 = Hs[(size_t)s3 * 64 + lane];
        ax += __uint_as_float(u0 << 16);  ay += __uint_as_float(u0 & 0xffff0000u);
        ax += __uint_as_float(u1 << 16);  ay += __uint_as_float(u1 & 0xffff0000u);
        ax += __uint_as_float(u2 << 16);  ay += __uint_as_float(u2 & 0xffff0000u);
        ax += __uint_as_float(u3 << 16);  ay += __uint_as_float(u3 & 0xffff0000u);
    }
    for (; k < m; ++k) {
        int s = __builtin_amdgcn_readlane(eid, k);
        unsigned int u = Hs[(size_t)s * 64 + lane];
        ax += __uint_as_float(u << 16);
        ay += __uint_as_float(u & 0xffff0000u);
    }
    for (; k < len; ++k) {                           // deg > 64 fallback (rare)
        int s = ebuf[beg + k];
        unsigned int u = Hs[(size_t)s * 64 + lane];
        ax += __uint_as_float(u << 16);
        ay += __uint_as_float(u & 0xffff0000u);
    }
    {   // self-loop term
        unsigned int u = Hs[(size_t)node * 64 + lane];
        ax += __uint_as_float(u << 16);
        ay += __uint_as_float(u & 0xffff0000u);
    }
    float wd = inv[node];
    float2 bv = ((const float2*)bias)[lane];
    float ox = fmaxf(fmaf(wd, ax, bv.x), 0.f);
    float oy = fmaxf(fmaf(wd, ay, bv.y), 0.f);
    outp[(size_t)node * 64 + lane] =
        (unsigned int)f2bf(ox) | ((unsigned int)f2bf(oy) << 16);
}

// ---------------- layer-2 aggregate + bias + log_softmax (readlane walk) ------
__global__ void agg2_final_kernel(const unsigned short* __restrict__ Hs,
                                  const int* __restrict__ ebuf, const int2* __restrict__ rowpair,
                                  const float* __restrict__ inv, const float* __restrict__ bp,
                                  float* __restrict__ outp, int n) {
    int node = __builtin_amdgcn_readfirstlane(blockIdx.x * 4 + (threadIdx.x >> 6));
    int lane = threadIdx.x & 63;
    if (node >= n) return;
    int2 rp = rowpair[node];
    int beg = rp.x, len = rp.y - rp.x;
    int eid = ebuf[beg + lane];
    int m = len < 64 ? len : 64;
    float acc = 0.f;
    int k = 0;
    for (; k + 4 <= m; k += 4) {
        int s0 = __builtin_amdgcn_readlane(eid, k);
        int s1 = __builtin_amdgcn_readlane(eid, k + 1);
        int s2 = __builtin_amdgcn_readlane(eid, k + 2);
        int s3 = __builtin_amdgcn_readlane(eid, k + 3);
        float v0 = bf2f(Hs[(size_t)s0 * 64 + lane]);
        float v1 = bf2f(Hs[(size_t)s1 * 64 + lane]);
        float v2 = bf2f(Hs[(size_t)s2 * 64 + lane]);
        float v3 = bf2f(Hs[(size_t)s3 * 64 + lane]);
        acc += v0 + v1 + v2 + v3;
    }
    for (; k < m; ++k) {
        int s = __builtin_amdgcn_readlane(eid, k);
        acc += bf2f(Hs[(size_t)s * 64 + lane]);
    }
    for (; k < len; ++k) {                           // deg > 64 fallback
        acc += bf2f(Hs[(size_t)ebuf[beg + k] * 64 + lane]);
    }
    acc += bf2f(Hs[(size_t)node * 64 + lane]);       // self-loop
    float fo = fmaf(inv[node], acc, bp[lane]);
    float mx = fo;
#pragma unroll
    for (int off = 32; off >= 1; off >>= 1) mx = fmaxf(mx, __shfl_xor(mx, off, 64));
    float ex = expf(fo - mx);
    float s = ex;
#pragma unroll
    for (int off = 32; off >= 1; off >>= 1) s += __shfl_xor(s, off, 64);
    outp[(size_t)node * COUT + lane] = fo - mx - logf(s);
}

static inline size_t align16(size_t x) { return (x + 15) & ~(size_t)15; }

extern "C" void kernel_launch(void* const* d_in, const int* in_sizes, int n_in,
                              void* d_out, int out_size, void* d_ws, size_t ws_size,
                              hipStream_t stream) {
    const float* x    = (const float*)d_in[0];
    const int*   eidx = (const int*)d_in[1];
    const float* W1   = (const float*)d_in[2];
    const float* b1   = (const float*)d_in[3];
    const float* W2   = (const float*)d_in[4];
    const float* b2   = (const float*)d_in[5];
    const float* linW = (const float*)d_in[6];
    const float* linb = (const float*)d_in[7];
    float* out = (float*)d_out;

    const int n = in_sizes[0] / CIN;   // 50000
    const int E = in_sizes[1] / 2;     // 800000
    const int* src = eidx;
    const int* dst = eidx + E;
    const int NBKT = (n + 255) >> 8;   // 196

    // ---- workspace carve-up
    char* ws = (char*)d_ws;
    size_t off = 0;
    int2*  rowpair = (int2*)(ws + off);  off = align16(off + (size_t)n * 8);
    float* inv     = (float*)(ws + off); off = align16(off + (size_t)n * 4);
    int*   bcursor = (int*)(ws + off);   off = align16(off + 256 * 4);
    unsigned short* Wt1 = (unsigned short*)(ws + off); off = align16(off + (size_t)CHID * CIN * 2);
    unsigned short* Wt2 = (unsigned short*)(ws + off); off = align16(off + (size_t)COUT * CHID * 2);
    float* bp      = (float*)(ws + off); off = align16(off + (size_t)COUT * 4);
    unsigned int* binned = (unsigned int*)(ws + off); off = align16(off + (size_t)256 * BCAP * 4);
    int*   ebuf    = (int*)(ws + off);   off = align16(off + (size_t)256 * BCAP * 4);
    unsigned short* h1s   = (unsigned short*)(ws + off); off = align16(off + (size_t)n * CHID * 2);
    unsigned short* agg1b = (unsigned short*)(ws + off); off = align16(off + (size_t)n * CHID * 2);
    unsigned short* h2p   = (unsigned short*)(ws + off); off = align16(off + (size_t)n * COUT * 2);

    // ---- weight prep + bcursor zeroing (single launch, replaces memset)
    wprep_kernel<<<CHID + 1, 128, 0, stream>>>(W1, W2, b2, linW, linb, Wt1, Wt2, bp, bcursor);

    // ---- CSR build: bin (fixed-cap regions) -> per-bucket CSR
    bin_kernel<<<(E + BINCHUNK - 1) / BINCHUNK, 256, 0, stream>>>(src, dst, bcursor, binned, E);
    csr_kernel<<<NBKT, 512, 0, stream>>>(binned, bcursor, rowpair, inv, ebuf, n);

    // ---- layer 1: MFMA GEMM + gather-aggregate
    gemm_mfma<CHID, false><<<(n + 63) / 64, 256, 0, stream>>>(x, Wt1, inv, h1s, n);
    agg1_kernel<<<(n + 3) / 4, 256, 0, stream>>>((const unsigned int*)h1s, ebuf, rowpair, inv, b1,
                                                 (unsigned int*)agg1b, n);

    // ---- layer 2: MFMA GEMM (bf16 A) + final
    gemm_mfma<COUT, true><<<(n + 63) / 64, 256, 0, stream>>>(agg1b, Wt2, inv, h2p, n);
    agg2_final_kernel<<<(n + 3) / 4, 256, 0, stream>>>(h2p, ebuf, rowpair, inv, bp, out, n);
}